// Round 1
// 108.679 us; speedup vs baseline: 1.0386x; 1.0386x over previous
//
#include <hip/hip_runtime.h>

#define NROWS 12288
#define BSZ   4096
#define DIM   128
#define NB    48                          // 256-row/col bands
#define NTILES (NB * (NB + 1) / 2)        // 1176 upper-triangular tiles
#define COLS_PER_BLOCK 256
#define NSTRIPS (COLS_PER_BLOCK / 32)     // 8 strips of 32 cols

typedef __bf16 bf16x8 __attribute__((ext_vector_type(8)));
typedef float  f32x4  __attribute__((ext_vector_type(4)));

__device__ __forceinline__ unsigned short f2bf(float f) {
  unsigned int u = __float_as_uint(f);
  u = u + 0x7FFFu + ((u >> 16) & 1u);   // round-to-nearest-even
  return (unsigned short)(u >> 16);
}
__device__ __forceinline__ float bf2f(unsigned short h) {
  return __uint_as_float(((unsigned int)h) << 16);
}

// ---------------------------------------------------------------------------
// Kernel 1 (fused prep + posmax): one wave per triplet index i.
// ---------------------------------------------------------------------------
__global__ void prep_k(const float* __restrict__ a, const float* __restrict__ p,
                       const float* __restrict__ nn,
                       unsigned short* __restrict__ embh, float* __restrict__ sq,
                       unsigned int* __restrict__ negbits,
                       float* __restrict__ posmax2, float* __restrict__ regpart) {
  const int w = threadIdx.x >> 6, lane = threadIdx.x & 63;
  const int i = blockIdx.x * 4 + w;
  const float2 av = reinterpret_cast<const float2*>(a  + (size_t)i * DIM)[lane];
  const float2 pv = reinterpret_cast<const float2*>(p  + (size_t)i * DIM)[lane];
  const float2 nv = reinterpret_cast<const float2*>(nn + (size_t)i * DIM)[lane];

  const unsigned short ha0 = f2bf(av.x), ha1 = f2bf(av.y);
  const unsigned short hp0 = f2bf(pv.x), hp1 = f2bf(pv.y);
  const unsigned short hn0 = f2bf(nv.x), hn1 = f2bf(nv.y);
  reinterpret_cast<ushort2*>(embh + (size_t)i * DIM)[lane]             = make_ushort2(ha0, ha1);
  reinterpret_cast<ushort2*>(embh + (size_t)(BSZ + i) * DIM)[lane]     = make_ushort2(hp0, hp1);
  reinterpret_cast<ushort2*>(embh + (size_t)(2 * BSZ + i) * DIM)[lane] = make_ushort2(hn0, hn1);

  // sq of ROUNDED values (so the GEMM-based d2 is consistent & >= 0)
  float rax = bf2f(ha0), ray = bf2f(ha1);
  float rpx = bf2f(hp0), rpy = bf2f(hp1);
  float rnx = bf2f(hn0), rny = bf2f(hn1);
  float sa = rax * rax + ray * ray;
  float sp = rpx * rpx + rpy * rpy;
  float sn = rnx * rnx + rny * rny;

  // reg from exact values
  float t0 = fabsf(av.x) - 1.f, t1 = fabsf(av.y) - 1.f;
  float t2 = fabsf(pv.x) - 1.f, t3 = fabsf(pv.y) - 1.f;
  float t4 = fabsf(nv.x) - 1.f, t5 = fabsf(nv.y) - 1.f;
  float rg = t0 * t0 + t1 * t1 + t2 * t2 + t3 * t3 + t4 * t4 + t5 * t5;

  // pos distances, exact fp32
  float dx, dy;
  dx = av.x - pv.x; dy = av.y - pv.y; float dap = dx * dx + dy * dy;
  dx = av.x - nv.x; dy = av.y - nv.y; float dan = dx * dx + dy * dy;
  dx = pv.x - nv.x; dy = pv.y - nv.y; float dpn = dx * dx + dy * dy;

  for (int m = 32; m; m >>= 1) {
    sa  += __shfl_xor(sa, m);  sp  += __shfl_xor(sp, m);  sn  += __shfl_xor(sn, m);
    rg  += __shfl_xor(rg, m);
    dap += __shfl_xor(dap, m); dan += __shfl_xor(dan, m); dpn += __shfl_xor(dpn, m);
  }
  if (lane == 0) {
    sq[i] = sa; sq[BSZ + i] = sp; sq[2 * BSZ + i] = sn;
    negbits[i] = negbits[BSZ + i] = negbits[2 * BSZ + i] = 0x7F800000u;  // +inf
    posmax2[i]           = fmaxf(dap, dan);
    posmax2[BSZ + i]     = fmaxf(dap, dpn);
    posmax2[2 * BSZ + i] = fmaxf(dan, dpn);
    regpart[i] = rg;
  }
}

// ---------------------------------------------------------------------------
// Kernel 2: neg_min^2 via SYMMETRIC upper-triangular tiling.
// The Gram/distance matrix is symmetric and the exclusion mask (j==i mod 4096)
// is symmetric, so only tiles (ti<=tj) of 256x256 are computed: 1176 of 2304
// (51% of the round-5 MFMA work). Each off-diagonal tile contributes BOTH its
// row-mins (rows ti-band, as before) and its col-mins (rows tj-band, via the
// mirrored reading). To let one value feed both folds, sq[row] is folded into
// the epilogue element: e = sq[col] - 2*dot + sq[row] = d^2(i,j) directly.
// Col path: per-strip fold over (mt,r), shfl-reduce over q, per-wave LDS slot
// (no atomics; 8 strips x 32 cols covers all 256 slots), block flush of 256
// atomicMin. Diagonal tiles skip the col path (row-min covers the square).
// Staging/dbuf/MFMA structure is unchanged from round 5 (NSTRIPS is now 8).
// ---------------------------------------------------------------------------
__global__ __launch_bounds__(256, 3) void negmin_k(
    const unsigned short* __restrict__ embh,
    const float* __restrict__ sq,
    unsigned int* __restrict__ negbits) {
  __shared__ __align__(16) char ldsB[2][8192];   // [buf][kc*1024 + lane*16]
  __shared__ float cminw[4][COLS_PER_BLOCK];     // per-wave col-min partials
  const int tid  = threadIdx.x;
  const int w    = tid >> 6;
  const int lane = tid & 63;
  const int c16  = lane & 15;
  const int q    = lane >> 4;

  // Decode linear blockIdx -> upper-triangular tile (ti <= tj). Wave-uniform
  // scalar loop, <=48 iterations, once per block.
  int rem = blockIdx.x, ti = 0;
  while (rem >= NB - ti) { rem -= NB - ti; ++ti; }
  const int tj   = ti + rem;
  const bool diag = (ti == tj);
  const int wRow    = ti * 256 + w * 64;         // this wave's 64 rows
  const int colBase = tj * 256;
  const int rot     = blockIdx.x & (NSTRIPS - 1);

  // A fragments: 64 rows x K=128. 4 mtiles x 4 ksteps, A[m=c16][k=q*8+j].
  bf16x8 afrag[4][4];
  {
    const char* abase = (const char*)embh + (size_t)(wRow + c16) * 256 + q * 16;
#pragma unroll
    for (int mt = 0; mt < 4; ++mt)
#pragma unroll
      for (int ks = 0; ks < 4; ++ks)
        afrag[mt][ks] = *reinterpret_cast<const bf16x8*>(abase + mt * 4096 + ks * 64);
  }

  // sq of this wave's own 64 rows (row = wRow + mt*16 + q*4 + r).
  float sqrow[4][4];
  {
    const int rbase = wRow + q * 4;
#pragma unroll
    for (int mt = 0; mt < 4; ++mt) {
      const f32x4 t = *reinterpret_cast<const f32x4*>(&sq[rbase + mt * 16]);
#pragma unroll
      for (int r = 0; r < 4; ++r) sqrow[mt][r] = t[r];
    }
  }

  float minv[4][4];
#pragma unroll
  for (int mt = 0; mt < 4; ++mt)
#pragma unroll
    for (int r = 0; r < 4; ++r) minv[mt][r] = __builtin_inff();

  // Stage strip sidx into LDS buffer b. 8 chunks of 1 KB; wave w issues
  // chunks 2w, 2w+1. Chunk kc: ks = kc>>1, col-half = kc&1. Dest is
  // wave-uniform base + lane*16 (global_load_lds constraint); the source
  // address per lane is chosen so LDS ends up exactly in B-fragment order.
  auto stage = [&](int sidx, int b) {
#pragma unroll
    for (int h = 0; h < 2; ++h) {
      const int kc = w * 2 + h;
      const char* gp = (const char*)embh +
          (size_t)(colBase + sidx * 32 + (kc & 1) * 16 + c16) * 256 +
          (kc >> 1) * 64 + q * 16;
      __builtin_amdgcn_global_load_lds(
          (const __attribute__((address_space(1))) unsigned int*)gp,
          (__attribute__((address_space(3))) unsigned int*)(&ldsB[b][kc * 1024]),
          16, 0, 0);
    }
  };

  int strip = rot;
  stage(strip, 0);
  __syncthreads();                                  // drain stage(strip 0)
  {
    int s1 = strip + 1; if (s1 >= NSTRIPS) s1 -= NSTRIPS;
    stage(s1, 1);                                   // in flight over compute(0)
  }

  for (int c = 0; c < NSTRIPS; ++c) {
    const int b = c & 1;
    const int colStart = colBase + strip * 32;
    const float sq0 = sq[colStart + c16];
    const float sq1 = sq[colStart + 16 + c16];

    f32x4 acc[4][2] = {};
#pragma unroll
    for (int ks = 0; ks < 4; ++ks)
#pragma unroll
      for (int ct = 0; ct < 2; ++ct) {
        const bf16x8 bfr =
            *reinterpret_cast<const bf16x8*>(&ldsB[b][(ks * 2 + ct) * 1024 + lane * 16]);
#pragma unroll
        for (int mt = 0; mt < 4; ++mt)
          acc[mt][ct] =
              __builtin_amdgcn_mfma_f32_16x16x32_bf16(afrag[mt][ks], bfr, acc[mt][ct], 0, 0, 0);
      }

    // Barrier: (a) all waves done reading buf b -> safe to overwrite;
    // (b) drains each wave's own stage(c+1) loads (issued a full strip ago).
    __syncthreads();
    if (c + 2 < NSTRIPS) {
      int s2 = strip + 2; if (s2 >= NSTRIPS) s2 -= NSTRIPS;
      stage(s2, b);
    }

    // Epilogue on registers (post-barrier, overlaps stage(c+2) latency).
    // e = d^2(row,col) exactly (sqcol - 2 dot + sqrow); fold into BOTH the
    // row-min (minv) and the per-strip col-min (cf0/cf1).
    // Exclusion j == i (mod 4096): lv = dd + ct*16 + c16 - q*4 vs K = mt*16+r.
    const int dd = (colStart - wRow) & 4095;
    float cf0 = __builtin_inff(), cf1 = __builtin_inff();
    if (dd < 76 || dd > 4064) {
#pragma unroll
      for (int mt = 0; mt < 4; ++mt)
#pragma unroll
        for (int ct = 0; ct < 2; ++ct) {
          const float sqb = ct ? sq1 : sq0;
          const int lvc = dd + ct * 16 + c16 - q * 4;
#pragma unroll
          for (int r = 0; r < 4; ++r) {
            float e = fmaf(-2.f, acc[mt][ct][r], sqb) + sqrow[mt][r];
            const int K = mt * 16 + r;
            if (lvc == K || lvc == K + 4096) e = __builtin_inff();
            minv[mt][r] = fminf(minv[mt][r], e);
            if (ct) cf1 = fminf(cf1, e); else cf0 = fminf(cf0, e);
          }
        }
    } else {
#pragma unroll
      for (int mt = 0; mt < 4; ++mt)
#pragma unroll
        for (int ct = 0; ct < 2; ++ct) {
          const float sqb = ct ? sq1 : sq0;
#pragma unroll
          for (int r = 0; r < 4; ++r) {
            float e = fmaf(-2.f, acc[mt][ct][r], sqb) + sqrow[mt][r];
            minv[mt][r] = fminf(minv[mt][r], e);
            if (ct) cf1 = fminf(cf1, e); else cf0 = fminf(cf0, e);
          }
        }
    }

    if (!diag) {
      // Reduce over the 4 q-groups (rows) sharing each column, then park in
      // this wave's LDS slot. Each strip owns 32 distinct slots -> all 256
      // slots written exactly once per wave, no init needed.
      cf0 = fminf(cf0, __shfl_xor(cf0, 16));
      cf0 = fminf(cf0, __shfl_xor(cf0, 32));
      cf1 = fminf(cf1, __shfl_xor(cf1, 16));
      cf1 = fminf(cf1, __shfl_xor(cf1, 32));
      if (q == 0) {
        cminw[w][strip * 32 + c16]      = cf0;
        cminw[w][strip * 32 + 16 + c16] = cf1;
      }
    }

    strip = strip + 1; if (strip >= NSTRIPS) strip -= NSTRIPS;
  }

  // Row-min tail: reduce over the 16 column-lanes sharing each row, then
  // atomicMin (uint bits order-preserving for floats >= 0). minv already
  // holds full d^2, so no sq[row] add here.
#pragma unroll
  for (int mt = 0; mt < 4; ++mt)
#pragma unroll
    for (int r = 0; r < 4; ++r) {
      float v = minv[mt][r];
      v = fminf(v, __shfl_xor(v, 1));
      v = fminf(v, __shfl_xor(v, 2));
      v = fminf(v, __shfl_xor(v, 4));
      v = fminf(v, __shfl_xor(v, 8));
      if (c16 == 0) {
        const int row = wRow + mt * 16 + q * 4 + r;   // C/D: row=(lane>>4)*4+r
        atomicMin(&negbits[row], __float_as_uint(fmaxf(v, 0.f)));
      }
    }

  // Col-min flush (mirrored rows, tj-band): combine the 4 waves' partials.
  __syncthreads();
  if (!diag) {
    const float m = fminf(fminf(cminw[0][tid], cminw[1][tid]),
                          fminf(cminw[2][tid], cminw[3][tid]));
    atomicMin(&negbits[colBase + tid], __float_as_uint(fmaxf(m, 0.f)));
  }
}

// ---------------------------------------------------------------------------
// Kernel 3: final scalar reduction. Single block, 1024 threads.
// ---------------------------------------------------------------------------
__global__ void final_k(const float* __restrict__ posmax2,
                        const unsigned int* __restrict__ negbits,
                        const float* __restrict__ regpart, float* __restrict__ out) {
  __shared__ float red[16], redr[16];
  const int tid = threadIdx.x;  // 1024
  float s = 0.f;
  for (int i = tid; i < NROWS; i += 1024) {
    const float pm = sqrtf(posmax2[i]);
    const float nm = sqrtf(__uint_as_float(negbits[i]));
    s += fmaxf(pm - nm + 0.4f, 0.f);
  }
  float rg = 0.f;
  for (int i = tid; i < BSZ; i += 1024) rg += regpart[i];
  for (int m = 32; m; m >>= 1) { s += __shfl_xor(s, m); rg += __shfl_xor(rg, m); }
  if ((tid & 63) == 0) { red[tid >> 6] = s; redr[tid >> 6] = rg; }
  __syncthreads();
  if (tid == 0) {
    float t = 0.f, tr = 0.f;
#pragma unroll
    for (int k = 0; k < 16; ++k) { t += red[k]; tr += redr[k]; }
    out[0] = t / (float)NROWS + 0.01f * (tr / (float)(NROWS * DIM));
  }
}

// ---------------------------------------------------------------------------
extern "C" void kernel_launch(void* const* d_in, const int* in_sizes, int n_in,
                              void* d_out, int out_size, void* d_ws, size_t ws_size,
                              hipStream_t stream) {
  const float* a  = (const float*)d_in[0];
  const float* p  = (const float*)d_in[1];
  const float* nn = (const float*)d_in[2];
  float* out = (float*)d_out;
  char* ws = (char*)d_ws;

  const size_t EMBH_BYTES = (size_t)NROWS * DIM * 2;       // 3,145,728
  unsigned short* embh    = (unsigned short*)ws;
  float*          sq      = (float*)(ws + EMBH_BYTES);
  unsigned int*   negbit  = (unsigned int*)(ws + EMBH_BYTES + (size_t)NROWS * 4);
  float*          pos2    = (float*)(ws + EMBH_BYTES + (size_t)NROWS * 8);
  float*          regpart = (float*)(ws + EMBH_BYTES + (size_t)NROWS * 12);

  prep_k<<<BSZ / 4, 256, 0, stream>>>(a, p, nn, embh, sq, negbit, pos2, regpart);
  negmin_k<<<dim3(NTILES), 256, 0, stream>>>(embh, sq, negbit);
  final_k<<<1, 1024, 0, stream>>>(pos2, negbit, regpart, out);
}